// Round 9
// baseline (462.690 us; speedup 1.0000x reference)
//
#include <hip/hip_runtime.h>

#define BATCH 4
#define NPTS  131072
#define KSEL  128
#define FDIM  96
#define QDIM  128

#define G   32                   // workgroups per batch
#define T   512                  // threads per workgroup
#define P   (NPTS / (G * T))     // 8 points per thread (registers)
#define NW  (T / 64)             // 8 waves per WG

#define AG __HIP_MEMORY_SCOPE_AGENT

// ---- workspace (136 KiB, well inside proven budget) ----
// slots[BATCH][2][G][4] u64 : step-parity double-buffered tagged payload
//   word0 = (d2_bits<<32) | (m<<8) | s   (m = NPTS-1-n: max key = max d2, min n)
//   word1..3 = (coord_bits<<32) | s
// fparts[BATCH][KSEL][G] u64 : feat argmax partials (key = d2<<32 | ~n)
#define SLOTS_SZ  (BATCH * 2 * G * 4 * 8)        // 8 KiB
#define FPART_SZ  (BATCH * KSEL * G * 8)         // 128 KiB
#define FPART_OFF (SLOTS_SZ)
#define WS_TOTAL  (SLOTS_SZ + FPART_SZ)

// d2 exactly as numpy: (dx*dx + dy*dy) + dz*dz, no FMA contraction
__device__ __forceinline__ float d2_np(float ax, float ay, float az,
                                       float bx, float by, float bz) {
    float dx = __fsub_rn(ax, bx);
    float dy = __fsub_rn(ay, by);
    float dz = __fsub_rn(az, bz);
    return __fadd_rn(__fadd_rn(__fmul_rn(dx, dx), __fmul_rn(dy, dy)),
                     __fmul_rn(dz, dz));
}

__global__ __launch_bounds__(T) void fps_kernel(
    const float* __restrict__ coords,          // [BATCH][NPTS][3]
    unsigned long long* __restrict__ slots,    // [BATCH][2][G][4]
    unsigned long long* __restrict__ fparts,   // [BATCH][KSEL][G]
    float* __restrict__ out_sc)                // [BATCH][KSEL][3]
{
    const int b    = blockIdx.x / G;
    const int wgb  = blockIdx.x % G;
    const int tid  = threadIdx.x;
    const int wid  = tid >> 6;
    const int lane = tid & 63;
    const float* cb = coords + (size_t)b * NPTS * 3;
    const int base = wgb * T + tid;            // stride G*T between my points

    __shared__ unsigned long long s_k[NW];
    __shared__ float s_x[NW], s_y[NW], s_z[NW];
    __shared__ unsigned long long s_ft[NW];
    __shared__ float s_samp[KSEL][3];
    __shared__ float s_cur[3];

    float px[P], py[P], pz[P], md[P];
    #pragma unroll
    for (int j = 0; j < P; ++j) {
        int n = base + j * (G * T);
        px[j] = cb[n * 3 + 0];
        py[j] = cb[n * 3 + 1];
        pz[j] = cb[n * 3 + 2];
        md[j] = 1e10f;
    }

    float cx = cb[0], cy = cb[1], cz = cb[2];  // sample 0 = index 0
    if (tid == 0) {
        s_samp[0][0] = cx; s_samp[0][1] = cy; s_samp[0][2] = cz;
    }
    __syncthreads();

    for (int s = 1; s < KSEL; ++s) {
        const int pb = s & 1;
        // update md; track per-lane argmax of md (with coords) and raw d2 (feat)
        float bm = -1.0f; unsigned bn = 0;
        float wx = 0.f, wy = 0.f, wz = 0.f;
        float bd = -1.0f; unsigned fn = 0;
        #pragma unroll
        for (int j = 0; j < P; ++j) {
            float d2 = d2_np(px[j], py[j], pz[j], cx, cy, cz);
            unsigned n = (unsigned)(base + j * (G * T));
            if (d2 > bd) { bd = d2; fn = n; }
            float m = fminf(md[j], d2);
            md[j] = m;
            if (m > bm) { bm = m; bn = n; wx = px[j]; wy = py[j]; wz = pz[j]; }
        }
        unsigned long long kmd =
            ((unsigned long long)__float_as_uint(bm) << 32) |
            ((unsigned long long)(NPTS - 1 - bn) << 8) | (unsigned)s;
        unsigned long long kft =
            ((unsigned long long)__float_as_uint(bd) << 32) | (unsigned)(~fn);
        #pragma unroll
        for (int off = 32; off > 0; off >>= 1) {
            unsigned long long o1 = __shfl_xor(kmd, off, 64);
            float ox = __shfl_xor(wx, off, 64);
            float oy = __shfl_xor(wy, off, 64);
            float oz = __shfl_xor(wz, off, 64);
            unsigned long long o2 = __shfl_xor(kft, off, 64);
            if (o1 > kmd) { kmd = o1; wx = ox; wy = oy; wz = oz; }
            if (o2 > kft) kft = o2;
        }
        if (lane == 0) {
            s_k[wid] = kmd; s_x[wid] = wx; s_y[wid] = wy; s_z[wid] = wz;
            s_ft[wid] = kft;
        }
        __syncthreads();                       // barrier 1: partials ready

        if (wid == 0) {
            // merge NW wave partials (carrying coords), publish tagged payload
            unsigned long long k1 = (lane < NW) ? s_k[lane] : 0;
            float mx = (lane < NW) ? s_x[lane] : 0.f;
            float my = (lane < NW) ? s_y[lane] : 0.f;
            float mz = (lane < NW) ? s_z[lane] : 0.f;
            #pragma unroll
            for (int off = 4; off > 0; off >>= 1) {
                unsigned long long o = __shfl_xor(k1, off, 64);
                float ox = __shfl_xor(mx, off, 64);
                float oy = __shfl_xor(my, off, 64);
                float oz = __shfl_xor(mz, off, 64);
                if (o > k1) { k1 = o; mx = ox; my = oy; mz = oz; }
            }
            if (lane == 0) {
                unsigned long long* sp = &slots[((size_t)(b * 2 + pb) * G + wgb) * 4];
                __hip_atomic_store(sp + 0, k1, __ATOMIC_RELAXED, AG);
                __hip_atomic_store(sp + 1,
                    ((unsigned long long)__float_as_uint(mx) << 32) | (unsigned)s,
                    __ATOMIC_RELAXED, AG);
                __hip_atomic_store(sp + 2,
                    ((unsigned long long)__float_as_uint(my) << 32) | (unsigned)s,
                    __ATOMIC_RELAXED, AG);
                __hip_atomic_store(sp + 3,
                    ((unsigned long long)__float_as_uint(mz) << 32) | (unsigned)s,
                    __ATOMIC_RELAXED, AG);
            }
            // wide poll: 64 lanes x 2 u64 = the whole 1 KiB row per iteration
            const unsigned long long* p =
                &slots[(size_t)(b * 2 + pb) * G * 4 + lane * 2];
            const bool ev = (lane & 1) == 0;
            const unsigned stag = (unsigned)s;
            unsigned long long k0, kv1;
            for (;;) {
                k0  = __hip_atomic_load(p,     __ATOMIC_RELAXED, AG);
                kv1 = __hip_atomic_load(p + 1, __ATOMIC_RELAXED, AG);
                bool ok = ev ? ((((unsigned)k0) & 0xFFu) == stag &&
                                ((unsigned)kv1) == stag)
                             : (((unsigned)k0) == stag &&
                                ((unsigned)kv1) == stag);
                if (__ballot(!ok) == 0) break;
            }
            // winner argmax over even lanes; coords from neighbor lanes' regs
            unsigned long long kk = ev ? k0 : 0;
            unsigned wl = (unsigned)lane;
            #pragma unroll
            for (int off = 32; off > 0; off >>= 1) {
                unsigned long long o = __shfl_xor(kk, off, 64);
                unsigned ol = __shfl_xor(wl, off, 64);
                if (o > kk) { kk = o; wl = ol; }
            }
            float fx = __uint_as_float((unsigned)(__shfl(kv1, (int)wl, 64) >> 32));
            unsigned long long yw = __shfl(k0,  (int)wl + 1, 64);
            unsigned long long zw = __shfl(kv1, (int)wl + 1, 64);
            if (lane == 0) {
                float fy = __uint_as_float((unsigned)(yw >> 32));
                float fz = __uint_as_float((unsigned)(zw >> 32));
                s_cur[0] = fx; s_cur[1] = fy; s_cur[2] = fz;
                s_samp[s][0] = fx; s_samp[s][1] = fy; s_samp[s][2] = fz;
            }
        } else if (wid == 1) {
            // feat merge/store: off the critical path
            unsigned long long k2 = (lane < NW) ? s_ft[lane] : 0;
            #pragma unroll
            for (int off = 4; off > 0; off >>= 1) {
                unsigned long long o = __shfl_xor(k2, off, 64);
                if (o > k2) k2 = o;
            }
            if (lane == 0)
                fparts[((size_t)b * KSEL + (s - 1)) * G + wgb] = k2;
        }
        __syncthreads();                       // barrier 2: winner broadcast
        cx = s_cur[0]; cy = s_cur[1]; cz = s_cur[2];
    }

    // feat partial for sample 127 (cx.. = sample 127 now)
    {
        float bd = -1.0f; unsigned fn = 0;
        #pragma unroll
        for (int j = 0; j < P; ++j) {
            float d2 = d2_np(px[j], py[j], pz[j], cx, cy, cz);
            unsigned n = (unsigned)(base + j * (G * T));
            if (d2 > bd) { bd = d2; fn = n; }
        }
        unsigned long long kft =
            ((unsigned long long)__float_as_uint(bd) << 32) | (unsigned)(~fn);
        #pragma unroll
        for (int off = 32; off > 0; off >>= 1) {
            unsigned long long o = __shfl_xor(kft, off, 64);
            if (o > kft) kft = o;
        }
        if (lane == 0) s_ft[wid] = kft;
        __syncthreads();
        if (tid == 0) {
            unsigned long long k = s_ft[0];
            #pragma unroll
            for (int w = 1; w < NW; ++w)
                if (s_ft[w] > k) k = s_ft[w];
            fparts[((size_t)b * KSEL + (KSEL - 1)) * G + wgb] = k;
        }
    }

    // wg0 dumps all sampled coords once (off critical path)
    if (wgb == 0 && tid < KSEL * 3) {
        const float* sf = &s_samp[0][0];
        out_sc[(size_t)b * KSEL * 3 + tid] = sf[tid];
    }
}

__global__ __launch_bounds__(QDIM) void mlp_kernel(
    const float* __restrict__ features,   // [BATCH][NPTS][FDIM]
    const float* __restrict__ W1,         // [FDIM][QDIM]
    const float* __restrict__ b1,         // [QDIM]
    const float* __restrict__ W2,         // [QDIM][QDIM]
    const float* __restrict__ b2,         // [QDIM]
    const unsigned long long* __restrict__ fparts,  // [BATCH][KSEL][G]
    float* __restrict__ out_q)            // [BATCH][KSEL][QDIM]
{
    const int bk = blockIdx.x;            // b*KSEL + k
    const int b  = bk / KSEL;
    const int q  = threadIdx.x;
    const int lane = q & 63;

    __shared__ float fr[FDIM];
    __shared__ float h[QDIM];
    __shared__ int s_idx;

    if (q < 64) {
        unsigned long long k = 0;
        if (lane < G) k = fparts[(size_t)bk * G + lane];
        #pragma unroll
        for (int off = 32; off > 0; off >>= 1) {
            unsigned long long o = __shfl_xor(k, off, 64);
            if (o > k) k = o;
        }
        if (lane == 0) s_idx = (int)(~(unsigned)(k & 0xFFFFFFFFull));
    }
    __syncthreads();

    const float* frow = features + ((size_t)b * NPTS + s_idx) * FDIM;
    if (q < FDIM) fr[q] = frow[q];
    __syncthreads();

    float acc = b1[q];
    #pragma unroll 8
    for (int f = 0; f < FDIM; ++f) acc += fr[f] * W1[f * QDIM + q];
    h[q] = fmaxf(acc, 0.0f);
    __syncthreads();

    float acc2 = b2[q];
    #pragma unroll 8
    for (int j = 0; j < QDIM; ++j) acc2 += h[j] * W2[j * QDIM + q];
    out_q[(size_t)bk * QDIM + q] = acc2;
}

extern "C" void kernel_launch(void* const* d_in, const int* in_sizes, int n_in,
                              void* d_out, int out_size, void* d_ws, size_t ws_size,
                              hipStream_t stream) {
    (void)in_sizes; (void)n_in; (void)out_size; (void)ws_size;
    const float* coords   = (const float*)d_in[0];
    const float* features = (const float*)d_in[1];
    const float* W1       = (const float*)d_in[2];
    const float* b1       = (const float*)d_in[3];
    const float* W2       = (const float*)d_in[4];
    const float* b2       = (const float*)d_in[5];

    float* out_q  = (float*)d_out;
    float* out_sc = out_q + (size_t)BATCH * KSEL * QDIM;

    char* ws = (char*)d_ws;
    unsigned long long* slots  = (unsigned long long*)ws;
    unsigned long long* fparts = (unsigned long long*)(ws + FPART_OFF);

    hipMemsetAsync(d_ws, 0, WS_TOTAL, stream);
    fps_kernel<<<BATCH * G, T, 0, stream>>>(coords, slots, fparts, out_sc);
    mlp_kernel<<<BATCH * KSEL, QDIM, 0, stream>>>(features, W1, b1, W2, b2,
                                                  fparts, out_q);
}